// Round 8
// baseline (892.204 us; speedup 1.0000x reference)
//
#include <hip/hip_runtime.h>
#include <hip/hip_fp16.h>
#include <math.h>

#define N_MEMBERS 2
#define N_NODES   65536
#define N_EDGES   1048576
#define N_LAYERS  12
#define D         64
#define OFF_STRIDE (N_NODES + 1)
#define NODE_MASK (N_NODES - 1)

// CSR build via dst-binned counting sort
#define NBINS       256          // bin = dst >> 8 (256 nodes per bin)
#define BIN_CAP     5120         // mean 4096, +16 sigma slack
#define EDGES_PER_WG 4096        // 256 threads x 16 edges

typedef _Float16 f16;
typedef f16   f16x8 __attribute__((ext_vector_type(8)));
typedef float f32x4 __attribute__((ext_vector_type(4)));

// ---------- preprocessing: binned CSR build ----------

__global__ __launch_bounds__(256) void bin_scatter_k(const int* __restrict__ ei,
                                                     int* __restrict__ binCursor,
                                                     unsigned int* __restrict__ binned) {
    int m = blockIdx.y;
    int t = threadIdx.x;
    int eBase = blockIdx.x * EDGES_PER_WG;
    __shared__ int hist[NBINS];
    __shared__ int base[NBINS];
    hist[t] = 0;
    __syncthreads();
    const int* srcp = ei + (size_t)(m * 2 + 0) * N_EDGES;
    const int* dstp = ei + (size_t)(m * 2 + 1) * N_EDGES;
    unsigned int pk[16];
    int bn[16], rk[16];
    #pragma unroll
    for (int i = 0; i < 16; i++) {
        int e = eBase + i * 256 + t;            // coalesced
        int src = srcp[e] & NODE_MASK;
        int dst = dstp[e] & NODE_MASK;
        int b = dst >> 8;
        bn[i] = b;
        pk[i] = ((unsigned)src << 8) | (unsigned)(dst & 255);
        rk[i] = atomicAdd(&hist[b], 1);         // local rank within WG's bin chunk
    }
    __syncthreads();
    base[t] = atomicAdd(&binCursor[m * NBINS + t], hist[t]);  // 256 global atomics/WG
    __syncthreads();
    unsigned int* bb = binned + (size_t)m * NBINS * BIN_CAP;
    #pragma unroll
    for (int i = 0; i < 16; i++) {
        int pos = base[bn[i]] + rk[i];
        if (pos < BIN_CAP)                       // overflow guard (16-sigma, never hit)
            bb[(size_t)bn[i] * BIN_CAP + pos] = pk[i];
    }
}

__global__ __launch_bounds__(256) void scan_bins_k(const int* __restrict__ cur,
                                                   int* __restrict__ bbase) {
    int m = blockIdx.x, t = threadIdx.x;
    __shared__ int sh[256];
    int v0 = cur[m * NBINS + t];
    sh[t] = v0;
    __syncthreads();
    for (int ofs = 1; ofs < 256; ofs <<= 1) {
        int v = sh[t];
        int a = (t >= ofs) ? sh[t - ofs] : 0;
        __syncthreads();
        sh[t] = v + a;
        __syncthreads();
    }
    bbase[m * NBINS + t] = sh[t] - v0;   // exclusive
}

__global__ __launch_bounds__(256) void bin_build_k(const unsigned int* __restrict__ binned,
                                                   const int* __restrict__ binCursor,
                                                   const int* __restrict__ bbase,
                                                   int* __restrict__ off,
                                                   float* __restrict__ dinv,
                                                   unsigned short* __restrict__ csr_src) {
    int m = blockIdx.y, b = blockIdx.x, t = threadIdx.x;
    int cnt   = binCursor[m * NBINS + b];
    int gbase = bbase[m * NBINS + b];
    const unsigned int* bb = binned + ((size_t)m * NBINS + b) * BIN_CAP;
    __shared__ int degl[256];
    __shared__ int offl[256];
    degl[t] = 0;
    __syncthreads();
    unsigned int ed[20];                          // rank<<24 | src<<8 | dstLow
    #pragma unroll
    for (int j = 0; j < 20; j++) {
        int i = t + j * 256;                      // coalesced
        ed[j] = 0;
        if (i < cnt) {
            unsigned int w = bb[i];
            int r = atomicAdd(&degl[w & 255], 1); // within-node rank (LDS)
            ed[j] = w | ((unsigned)r << 24);
        }
    }
    __syncthreads();
    int myDeg = degl[t];
    offl[t] = myDeg;
    __syncthreads();
    for (int ofs = 1; ofs < 256; ofs <<= 1) {     // inclusive scan
        int v = offl[t];
        int a = (t >= ofs) ? offl[t - ofs] : 0;
        __syncthreads();
        offl[t] = v + a;
        __syncthreads();
    }
    int myOff = gbase + offl[t] - myDeg;          // global exclusive offset
    int node = b * 256 + t;
    off[m * OFF_STRIDE + node] = myOff;
    if (b == NBINS - 1 && t == 255) off[m * OFF_STRIDE + N_NODES] = N_EDGES;
    dinv[m * N_NODES + node] = 1.0f / sqrtf((float)myDeg + 1.0f);
    offl[t] = myOff;
    __syncthreads();
    unsigned short* cs = csr_src + (size_t)m * N_EDGES;
    #pragma unroll
    for (int j = 0; j < 20; j++) {
        int i = t + j * 256;
        if (i < cnt) {
            int dl  = ed[j] & 255;
            int src = (ed[j] >> 8) & 0xFFFF;
            int r   = ed[j] >> 24;
            cs[offl[dl] + r] = (unsigned short)src;   // within ~8KB window
        }
    }
}

// ---------- prescale: g = fp16(dinv * x) (layer-0 input table) ----------
__global__ __launch_bounds__(256) void prescale_k(const float* __restrict__ x,
                                                  const float* __restrict__ dinv,
                                                  __half* __restrict__ g) {
    int i = blockIdx.x * 256 + threadIdx.x;       // one per 8 floats
    float dv = dinv[i >> 3];                      // 64 floats per node
    float4 a = ((const float4*)x)[i * 2];
    float4 b = ((const float4*)x)[i * 2 + 1];
    union { __half2 h2[4]; uint4 u; } p;
    p.h2[0] = __floats2half2_rn(dv * a.x, dv * a.y);
    p.h2[1] = __floats2half2_rn(dv * a.z, dv * a.w);
    p.h2[2] = __floats2half2_rn(dv * b.x, dv * b.y);
    p.h2[3] = __floats2half2_rn(dv * b.z, dv * b.w);
    ((uint4*)g)[i] = p.u;
}

// ---------- fused layer: gather -> LDS S-tile -> MFMA -> g_next ----------
// Per block (256 thr): 32 nodes of one member.
//   phase 1: stage Whi/Wlo (split fp16) in LDS; issue gather (independent).
//   gather:  4 waves x 4 passes x 2-node interleave (proven R7 shape);
//            S = dinv .* (sum g[src] + g[self]) written to Sl[32][72] fp16.
//   barrier; phase 2: transposed MFMA D = W^T S^T (R6 shape) from LDS;
//            mid: g_next = fp16(dinv .* relu(D + b)); last: out fp32 = D + b.
__device__ __forceinline__ void cvt8(uint4 u, float* f) {
    const __half2* h2 = (const __half2*)&u;
    #pragma unroll
    for (int i = 0; i < 4; i++) {
        float2 t = __half22float2(h2[i]);
        f[2 * i]     = t.x;
        f[2 * i + 1] = t.y;
    }
}

__global__ __launch_bounds__(256) void layer_k(const __half* __restrict__ g,
                                               const float* __restrict__ Wall,
                                               const float* __restrict__ dinv,
                                               const float* __restrict__ ball,
                                               const int* __restrict__ off,
                                               const unsigned short* __restrict__ csr_src,
                                               __half* __restrict__ gout,
                                               float* __restrict__ fout,
                                               int layer, int last) {
    __shared__ __align__(16) _Float16 Whi[D][72];
    __shared__ __align__(16) _Float16 Wlo[D][72];
    __shared__ __align__(16) _Float16 Sl[32][72];

    int bflat = blockIdx.x;
    int xcd   = bflat & 7;                 // XCD round-robin heuristic
    int m     = xcd >> 2;                  // member pinned to XCD half
    int slot  = ((bflat >> 3) << 2) | (xcd & 3);   // [0, N_NODES/32)
    int n0    = slot * 32;

    // ---- W staging (independent of gather; both precede the one barrier) ----
    const float* Wg = Wall + (size_t)(m * N_LAYERS + layer) * D * D;
    for (int idx = threadIdx.x; idx < D * D / 4; idx += 256) {
        float4 v = ((const float4*)Wg)[idx];
        int k  = idx >> 4;
        int c0 = (idx & 15) << 2;
        float vv[4] = {v.x, v.y, v.z, v.w};
        #pragma unroll
        for (int i = 0; i < 4; i++) {
            f16 hi = (f16)vv[i];
            Whi[c0 + i][k] = hi;
            Wlo[c0 + i][k] = (f16)(vv[i] - (float)hi);
        }
    }

    int wav  = threadIdx.x >> 6;
    int lane = threadIdx.x & 63;
    int fg   = lane & 7;          // 16B chunk (8 halfs) of the 128B row
    int sub  = lane >> 3;         // 8 edges in flight per node
    const __half*         gm = g + (size_t)m * N_NODES * D;
    const int*            ob = off + m * OFF_STRIDE;
    const unsigned short* sb = csr_src + (size_t)m * N_EDGES;

    // ---- gather: 4 passes of 2-node interleave per wave (8 nodes/wave) ----
    for (int p = 0; p < 4; p++) {
        int nA = n0 + wav * 8 + p * 2;
        int nB = nA + 1;

        float accA[8], accB[8];
        #pragma unroll
        for (int i = 0; i < 8; i++) { accA[i] = 0.f; accB[i] = 0.f; }

        int eA0 = ob[nA], eA1 = ob[nA + 1], eB1 = ob[nB + 1];
        int eB0 = eA1;   // CSR contiguity
        #pragma unroll 2
        for (int eA = eA0, eB = eB0; (eA < eA1) || (eB < eB1); eA += 8, eB += 8) {
            int ia = eA + sub, ib = eB + sub;
            int idxA = (ia < eA1) ? ia : (eA1 - 1);
            int idxB = (ib < eB1) ? ib : (eB1 - 1);
            float wA = (ia < eA1) ? 1.0f : 0.0f;
            float wB = (ib < eB1) ? 1.0f : 0.0f;
            int sA = sb[idxA];
            int sB = sb[idxB];
            uint4 gA = *(const uint4*)(gm + (size_t)sA * D + fg * 8);
            uint4 gB = *(const uint4*)(gm + (size_t)sB * D + fg * 8);
            float fA[8], fB[8];
            cvt8(gA, fA);
            cvt8(gB, fB);
            #pragma unroll
            for (int i = 0; i < 8; i++) {
                accA[i] = fmaf(wA, fA[i], accA[i]);
                accB[i] = fmaf(wB, fB[i], accB[i]);
            }
        }
        #pragma unroll
        for (int msk = 8; msk < 64; msk <<= 1)
            #pragma unroll
            for (int i = 0; i < 8; i++) {
                accA[i] += __shfl_xor(accA[i], msk);
                accB[i] += __shfl_xor(accB[i], msk);
            }

        float dvA = dinv[m * N_NODES + nA];
        float dvB = dinv[m * N_NODES + nB];
        uint4 sgA = *(const uint4*)(gm + (size_t)nA * D + fg * 8);
        uint4 sgB = *(const uint4*)(gm + (size_t)nB * D + fg * 8);
        float sfA[8], sfB[8];
        cvt8(sgA, sfA);
        cvt8(sgB, sfB);
        if (sub == 0) {
            union { __half2 h2[4]; uint4 u; } q;
            #pragma unroll
            for (int i = 0; i < 4; i++)
                q.h2[i] = __floats2half2_rn(dvA * (accA[2 * i]     + sfA[2 * i]),
                                            dvA * (accA[2 * i + 1] + sfA[2 * i + 1]));
            *(uint4*)&Sl[nA - n0][fg * 8] = q.u;
        } else if (sub == 1) {
            union { __half2 h2[4]; uint4 u; } q;
            #pragma unroll
            for (int i = 0; i < 4; i++)
                q.h2[i] = __floats2half2_rn(dvB * (accB[2 * i]     + sfB[2 * i]),
                                            dvB * (accB[2 * i + 1] + sfB[2 * i + 1]));
            *(uint4*)&Sl[nB - n0][fg * 8] = q.u;
        }
    }
    __syncthreads();

    // ---- MFMA phase: wave -> (node-group ng, t-pair t0) ----
    int nn   = lane & 15;
    int quad = lane >> 4;
    int ng   = wav & 1;                 // 16-node group
    int t0   = (wav >> 1) * 2;          // two col-tiles per wave

    const float* bp = ball + (size_t)(m * N_LAYERS + layer) * D;
    __half*      gmo = gout + (size_t)m * N_NODES * D;
    float*       fmo = fout + (size_t)m * N_NODES * D;

    const _Float16* srow = &Sl[ng * 16 + nn][0];
    f16x8 a0 = *(const f16x8*)(srow + quad * 8);        // k = quad*8..+7
    f16x8 a1 = *(const f16x8*)(srow + 32 + quad * 8);   // k = 32+quad*8..+7

    int   node = n0 + ng * 16 + nn;
    float dv   = dinv[m * N_NODES + node];

    #pragma unroll
    for (int tt = 0; tt < 2; tt++) {
        int t = t0 + tt;
        f16x8 Bh0 = *(const f16x8*)&Whi[t * 16 + nn][quad * 8];
        f16x8 Bh1 = *(const f16x8*)&Whi[t * 16 + nn][32 + quad * 8];
        f16x8 Bl0 = *(const f16x8*)&Wlo[t * 16 + nn][quad * 8];
        f16x8 Bl1 = *(const f16x8*)&Wlo[t * 16 + nn][32 + quad * 8];
        f32x4 c = {0.f, 0.f, 0.f, 0.f};
        c = __builtin_amdgcn_mfma_f32_16x16x32_f16(Bh0, a0, c, 0, 0, 0);
        c = __builtin_amdgcn_mfma_f32_16x16x32_f16(Bh1, a1, c, 0, 0, 0);
        c = __builtin_amdgcn_mfma_f32_16x16x32_f16(Bl0, a0, c, 0, 0, 0);
        c = __builtin_amdgcn_mfma_f32_16x16x32_f16(Bl1, a1, c, 0, 0, 0);
        float4 b4 = *(const float4*)(bp + t * 16 + quad * 4);
        float v0 = (float)c[0] + b4.x;
        float v1 = (float)c[1] + b4.y;
        float v2 = (float)c[2] + b4.z;
        float v3 = (float)c[3] + b4.w;
        int col = t * 16 + quad * 4;
        if (last) {
            *(float4*)(fmo + (size_t)node * D + col) = make_float4(v0, v1, v2, v3);
        } else {
            union { __half2 h2[2]; uint2 u; } p;
            p.h2[0] = __floats2half2_rn(fmaxf(v0, 0.f) * dv, fmaxf(v1, 0.f) * dv);
            p.h2[1] = __floats2half2_rn(fmaxf(v2, 0.f) * dv, fmaxf(v3, 0.f) * dv);
            *(uint2*)(gmo + (size_t)node * D + col) = p.u;
        }
    }
}

// ---------- host ----------

extern "C" void kernel_launch(void* const* d_in, const int* in_sizes, int n_in,
                              void* d_out, int out_size, void* d_ws, size_t ws_size,
                              hipStream_t stream) {
    (void)in_sizes; (void)n_in; (void)out_size; (void)ws_size;
    const float* x  = (const float*)d_in[0];
    const int*   ei = (const int*)d_in[1];
    const float* W  = (const float*)d_in[2];
    const float* b  = (const float*)d_in[3];
    float* out = (float*)d_out;

    char* ws = (char*)d_ws;
    size_t o = 0;
    auto take = [&](size_t bytes) -> void* {
        void* p = ws + o;
        o = (o + bytes + 255) & ~(size_t)255;
        return p;
    };
    float*          dinv      = (float*) take((size_t)N_MEMBERS * N_NODES * 4);
    int*            off       = (int*)   take((size_t)N_MEMBERS * OFF_STRIDE * 4);
    int*            binCursor = (int*)   take((size_t)N_MEMBERS * NBINS * 4);
    int*            bbase     = (int*)   take((size_t)N_MEMBERS * NBINS * 4);
    unsigned short* csr_src   = (unsigned short*)take((size_t)N_MEMBERS * N_EDGES * 2);
    __half*         g0        = (__half*)take((size_t)N_MEMBERS * N_NODES * D * 2);
    __half*         g1        = (__half*)take((size_t)N_MEMBERS * N_NODES * D * 2);
    // binned staging (10.5 MB) aliases g1 (16 MB): binned dies at bin_build_k;
    // g1 is first written by layer_k (layer 0), strictly after.
    unsigned int*   binned    = (unsigned int*)g1;

    hipMemsetAsync(binCursor, 0, (size_t)N_MEMBERS * NBINS * 4, stream);

    bin_scatter_k<<<dim3(N_EDGES / EDGES_PER_WG, N_MEMBERS), 256, 0, stream>>>(
        ei, binCursor, binned);
    scan_bins_k<<<dim3(N_MEMBERS), 256, 0, stream>>>(binCursor, bbase);
    bin_build_k<<<dim3(NBINS, N_MEMBERS), 256, 0, stream>>>(
        binned, binCursor, bbase, off, dinv, csr_src);
    // g_0 = fp16(dinv .* x)  (needs dinv -> after bin_build_k)
    prescale_k<<<dim3((N_MEMBERS * N_NODES * D / 8) / 256), 256, 0, stream>>>(
        x, dinv, g0);

    __half* gin  = g0;
    __half* gout_ = g1;
    for (int j = 0; j < N_LAYERS; j++) {
        layer_k<<<dim3(N_MEMBERS * (N_NODES / 32)), 256, 0, stream>>>(
            gin, W, dinv, b, off, csr_src, gout_, out, j, (j == N_LAYERS - 1) ? 1 : 0);
        __half* tmp = gin; gin = gout_; gout_ = tmp;
    }
}

// Round 9
// 819.100 us; speedup vs baseline: 1.0892x; 1.0892x over previous
//
#include <hip/hip_runtime.h>
#include <hip/hip_fp16.h>
#include <math.h>

#define N_MEMBERS 2
#define N_NODES   65536
#define N_EDGES   1048576
#define N_LAYERS  12
#define D         64
#define OFF_STRIDE (N_NODES + 1)
#define NODE_MASK (N_NODES - 1)

// CSR build via dst-binned counting sort
#define NBINS       256          // bin = dst >> 8 (256 nodes per bin)
#define BIN_CAP     5120         // mean 4096, +16 sigma slack
#define EDGES_PER_WG 4096        // 256 threads x 16 edges

typedef _Float16 f16;
typedef f16   f16x8 __attribute__((ext_vector_type(8)));
typedef float f32x4 __attribute__((ext_vector_type(4)));

// ---------- preprocessing: binned CSR build ----------

__global__ __launch_bounds__(256) void bin_scatter_k(const int* __restrict__ ei,
                                                     int* __restrict__ binCursor,
                                                     unsigned int* __restrict__ binned) {
    int m = blockIdx.y;
    int t = threadIdx.x;
    int eBase = blockIdx.x * EDGES_PER_WG;
    __shared__ int hist[NBINS];
    __shared__ int base[NBINS];
    hist[t] = 0;
    __syncthreads();
    const int* srcp = ei + (size_t)(m * 2 + 0) * N_EDGES;
    const int* dstp = ei + (size_t)(m * 2 + 1) * N_EDGES;
    unsigned int pk[16];
    int bn[16], rk[16];
    #pragma unroll
    for (int i = 0; i < 16; i++) {
        int e = eBase + i * 256 + t;            // coalesced
        int src = srcp[e] & NODE_MASK;
        int dst = dstp[e] & NODE_MASK;
        int b = dst >> 8;
        bn[i] = b;
        pk[i] = ((unsigned)src << 8) | (unsigned)(dst & 255);
        rk[i] = atomicAdd(&hist[b], 1);         // local rank within WG's bin chunk
    }
    __syncthreads();
    base[t] = atomicAdd(&binCursor[m * NBINS + t], hist[t]);  // 256 global atomics/WG
    __syncthreads();
    unsigned int* bb = binned + (size_t)m * NBINS * BIN_CAP;
    #pragma unroll
    for (int i = 0; i < 16; i++) {
        int pos = base[bn[i]] + rk[i];
        if (pos < BIN_CAP)                       // overflow guard (16-sigma, never hit)
            bb[(size_t)bn[i] * BIN_CAP + pos] = pk[i];
    }
}

__global__ __launch_bounds__(256) void scan_bins_k(const int* __restrict__ cur,
                                                   int* __restrict__ bbase) {
    int m = blockIdx.x, t = threadIdx.x;
    __shared__ int sh[256];
    int v0 = cur[m * NBINS + t];
    sh[t] = v0;
    __syncthreads();
    for (int ofs = 1; ofs < 256; ofs <<= 1) {
        int v = sh[t];
        int a = (t >= ofs) ? sh[t - ofs] : 0;
        __syncthreads();
        sh[t] = v + a;
        __syncthreads();
    }
    bbase[m * NBINS + t] = sh[t] - v0;   // exclusive
}

__global__ __launch_bounds__(256) void bin_build_k(const unsigned int* __restrict__ binned,
                                                   const int* __restrict__ binCursor,
                                                   const int* __restrict__ bbase,
                                                   int* __restrict__ off,
                                                   float* __restrict__ dinv,
                                                   unsigned short* __restrict__ csr_src) {
    int m = blockIdx.y, b = blockIdx.x, t = threadIdx.x;
    int cnt   = binCursor[m * NBINS + b];
    int gbase = bbase[m * NBINS + b];
    const unsigned int* bb = binned + ((size_t)m * NBINS + b) * BIN_CAP;
    __shared__ int degl[256];
    __shared__ int offl[256];
    degl[t] = 0;
    __syncthreads();
    unsigned int ed[20];                          // rank<<24 | src<<8 | dstLow
    #pragma unroll
    for (int j = 0; j < 20; j++) {
        int i = t + j * 256;                      // coalesced
        ed[j] = 0;
        if (i < cnt) {
            unsigned int w = bb[i];
            int r = atomicAdd(&degl[w & 255], 1); // within-node rank (LDS)
            ed[j] = w | ((unsigned)r << 24);
        }
    }
    __syncthreads();
    int myDeg = degl[t];
    offl[t] = myDeg;
    __syncthreads();
    for (int ofs = 1; ofs < 256; ofs <<= 1) {     // inclusive scan
        int v = offl[t];
        int a = (t >= ofs) ? offl[t - ofs] : 0;
        __syncthreads();
        offl[t] = v + a;
        __syncthreads();
    }
    int myOff = gbase + offl[t] - myDeg;          // global exclusive offset
    int node = b * 256 + t;
    off[m * OFF_STRIDE + node] = myOff;
    if (b == NBINS - 1 && t == 255) off[m * OFF_STRIDE + N_NODES] = N_EDGES;
    dinv[m * N_NODES + node] = 1.0f / sqrtf((float)myDeg + 1.0f);
    offl[t] = myOff;
    __syncthreads();
    unsigned short* cs = csr_src + (size_t)m * N_EDGES;
    #pragma unroll
    for (int j = 0; j < 20; j++) {
        int i = t + j * 256;
        if (i < cnt) {
            int dl  = ed[j] & 255;
            int src = (ed[j] >> 8) & 0xFFFF;
            int r   = ed[j] >> 24;
            cs[offl[dl] + r] = (unsigned short)src;   // within ~8KB window
        }
    }
}

// ---------- presplit: W -> fragment-ordered split-fp16 table (once) --------
// Layout: Wsplit[ml][hl][t][s][lane][8 halves]; ml = m*N_LAYERS+layer.
// Fragment value: lane=(nn,quad): W^T[t*16+nn][s*32+quad*8 + j] = W[k][c],
// c = t*16+nn, k = s*32+quad*8+j.
__global__ __launch_bounds__(256) void presplit_k(const float* __restrict__ Wall,
                                                  __half* __restrict__ Wsplit) {
    int gid = blockIdx.x * 256 + threadIdx.x;     // 24*512 = 12288 threads
    int ml   = gid >> 9;
    int r    = gid & 511;
    int t    = (r >> 7) & 3;
    int s    = (r >> 6) & 1;
    int lane = r & 63;
    int c  = t * 16 + (lane & 15);
    int k0 = s * 32 + (lane >> 4) * 8;
    const float* Wg = Wall + (size_t)ml * D * D;
    __half* base = Wsplit + (size_t)ml * 8192;    // 2*4*2*64*8
    int fo = ((t * 2 + s) * 64 + lane) * 8;
    __half hi8[8], lo8[8];
    #pragma unroll
    for (int j = 0; j < 8; j++) {
        float v = Wg[(k0 + j) * D + c];
        f16 h = (f16)v;
        hi8[j] = *(__half*)&h;
        f16 l = (f16)(v - (float)h);
        lo8[j] = *(__half*)&l;
    }
    *(uint4*)(base + fo)        = *(uint4*)hi8;
    *(uint4*)(base + 4096 + fo) = *(uint4*)lo8;
}

// ---------- prescale: g = fp16(dinv * x) (layer-0 input table) ----------
__global__ __launch_bounds__(256) void prescale_k(const float* __restrict__ x,
                                                  const float* __restrict__ dinv,
                                                  __half* __restrict__ g) {
    int i = blockIdx.x * 256 + threadIdx.x;       // one per 8 floats
    float dv = dinv[i >> 3];                      // 64 floats per node
    float4 a = ((const float4*)x)[i * 2];
    float4 b = ((const float4*)x)[i * 2 + 1];
    union { __half2 h2[4]; uint4 u; } p;
    p.h2[0] = __floats2half2_rn(dv * a.x, dv * a.y);
    p.h2[1] = __floats2half2_rn(dv * a.z, dv * a.w);
    p.h2[2] = __floats2half2_rn(dv * b.x, dv * b.y);
    p.h2[3] = __floats2half2_rn(dv * b.z, dv * b.w);
    ((uint4*)g)[i] = p.u;
}

// ---------- per-layer aggregate: S = dinv .* (sum g[src] + g), 4-node/wave --
// 4-node interleave -> 2x R7's loads in flight. Butterfly reduce; epilogue
// fans out across sub = 0..3. Member -> XCD-half pinning kept.
__device__ __forceinline__ void cvt8(uint4 u, float* f) {
    const __half2* h2 = (const __half2*)&u;
    #pragma unroll
    for (int i = 0; i < 4; i++) {
        float2 t = __half22float2(h2[i]);
        f[2 * i]     = t.x;
        f[2 * i + 1] = t.y;
    }
}

__global__ __launch_bounds__(256) void aggregate_k(const __half* __restrict__ g,
                                                   __half* __restrict__ S,
                                                   const int* __restrict__ off,
                                                   const unsigned short* __restrict__ csr_src,
                                                   const float* __restrict__ dinv) {
    int bflat = blockIdx.x;
    int xcd   = bflat & 7;                 // round-robin XCD heuristic
    int m     = xcd >> 2;                  // member pinned to XCD half
    int slot  = ((bflat >> 3) << 2) | (xcd & 3);   // [0, N_NODES/16)
    int wav   = threadIdx.x >> 6;
    int n0    = slot * 16 + wav * 4;       // this wave's 4 nodes
    int lane = threadIdx.x & 63;
    int fg   = lane & 7;          // 16B chunk (8 halfs) of the 128B row
    int sub  = lane >> 3;         // 8 edges in flight per node
    const __half*         gm = g + (size_t)m * N_NODES * D;
    const int*            ob = off + m * OFF_STRIDE;
    const unsigned short* sb = csr_src + (size_t)m * N_EDGES;

    float acc[4][8];
    #pragma unroll
    for (int j = 0; j < 4; j++)
        #pragma unroll
        for (int i = 0; i < 8; i++) acc[j][i] = 0.f;

    int o[5];
    #pragma unroll
    for (int j = 0; j < 5; j++) o[j] = ob[n0 + j];
    int dm01 = max(o[1] - o[0], o[2] - o[1]);
    int dm23 = max(o[3] - o[2], o[4] - o[3]);
    int iters = (max(dm01, dm23) + 7) >> 3;

    #pragma unroll 2
    for (int it = 0; it < iters; it++) {
        int ofs = it * 8 + sub;
        #pragma unroll
        for (int j = 0; j < 4; j++) {
            int ia  = o[j] + ofs;
            int lim = o[j + 1];
            int idx = (ia < lim) ? ia : (lim - 1);
            float w = (ia < lim) ? 1.0f : 0.0f;
            int s   = sb[idx];
            uint4 gv = *(const uint4*)(gm + (size_t)s * D + fg * 8);
            float f[8];
            cvt8(gv, f);
            #pragma unroll
            for (int i = 0; i < 8; i++) acc[j][i] = fmaf(w, f[i], acc[j][i]);
        }
    }
    #pragma unroll
    for (int msk = 8; msk < 64; msk <<= 1)
        #pragma unroll
        for (int j = 0; j < 4; j++)
            #pragma unroll
            for (int i = 0; i < 8; i++) acc[j][i] += __shfl_xor(acc[j][i], msk);

    __half* Sm = S + (size_t)m * N_NODES * D;
    // sub j finalizes node n0+j (constant-index branches; rule #20)
    #pragma unroll
    for (int j = 0; j < 4; j++) {
        if (sub == j) {
            int n = n0 + j;
            float dv = dinv[m * N_NODES + n];
            uint4 sg = *(const uint4*)(gm + (size_t)n * D + fg * 8);
            float sf[8];
            cvt8(sg, sf);
            union { __half2 h2[4]; uint4 u; } p;
            #pragma unroll
            for (int i = 0; i < 4; i++)
                p.h2[i] = __floats2half2_rn(dv * (acc[j][2 * i]     + sf[2 * i]),
                                            dv * (acc[j][2 * i + 1] + sf[2 * i + 1]));
            *(uint4*)(Sm + (size_t)n * D + fg * 8) = p.u;
        }
    }
}

// ---------- per-layer GEMM: fragment-ordered W loads (no LDS, no barrier) ---
// Transposed MFMA D = W^T S^T (R6/R7 shape). W fragments come pre-split and
// pre-laid-out from Wsplit: 32 coalesced 16B loads/lane, L2-broadcast.
// mid layers: g_next = fp16( dinv .* relu(S@W + b) )
// last layer: out    = fp32( S@W + b )
__global__ __launch_bounds__(256) void gemm_f16_k(const __half* __restrict__ S,
                                                  const __half* __restrict__ Wsplit,
                                                  const float* __restrict__ dinv,
                                                  const float* __restrict__ ball,
                                                  __half* __restrict__ gout,
                                                  float* __restrict__ fout,
                                                  int layer, int last) {
    int m = blockIdx.y;
    int lane = threadIdx.x & 63;
    int wav  = threadIdx.x >> 6;
    int nn   = lane & 15;
    int quad = lane >> 4;

    const __half* Wf = Wsplit + (size_t)(m * N_LAYERS + layer) * 8192;
    f16x8 Bh[8], Bl[8];
    #pragma unroll
    for (int t = 0; t < 4; t++)
        #pragma unroll
        for (int s = 0; s < 2; s++) {
            int fo = ((t * 2 + s) * 64 + lane) * 8;
            Bh[t * 2 + s] = *(const f16x8*)(Wf + fo);
            Bl[t * 2 + s] = *(const f16x8*)(Wf + 4096 + fo);
        }

    const __half* Sm = S + (size_t)m * N_NODES * D;
    const float*  dm = dinv + m * N_NODES;
    const float*  bp = ball + (size_t)(m * N_LAYERS + layer) * D;
    __half*       gm = gout + (size_t)m * N_NODES * D;
    float*        fm = fout + (size_t)m * N_NODES * D;

    float4 b4[4];   // bias for cols t*16+quad*4 .. +3
    #pragma unroll
    for (int t = 0; t < 4; t++)
        b4[t] = *(const float4*)(bp + t * 16 + quad * 4);

    int base = blockIdx.x * 128 + wav * 32;
    #pragma unroll
    for (int g = 0; g < 2; g++) {
        int node = base + g * 16 + nn;
        const __half* srow = Sm + (size_t)node * D;
        f16x8 a0 = *(const f16x8*)(srow + quad * 8);        // k = quad*8..+7
        f16x8 a1 = *(const f16x8*)(srow + 32 + quad * 8);   // k = 32+quad*8..+7
        float dv = dm[node];
        #pragma unroll
        for (int t = 0; t < 4; t++) {
            f32x4 c = {0.f, 0.f, 0.f, 0.f};
            c = __builtin_amdgcn_mfma_f32_16x16x32_f16(Bh[t * 2 + 0], a0, c, 0, 0, 0);
            c = __builtin_amdgcn_mfma_f32_16x16x32_f16(Bh[t * 2 + 1], a1, c, 0, 0, 0);
            c = __builtin_amdgcn_mfma_f32_16x16x32_f16(Bl[t * 2 + 0], a0, c, 0, 0, 0);
            c = __builtin_amdgcn_mfma_f32_16x16x32_f16(Bl[t * 2 + 1], a1, c, 0, 0, 0);
            float v0 = (float)c[0] + b4[t].x;
            float v1 = (float)c[1] + b4[t].y;
            float v2 = (float)c[2] + b4[t].z;
            float v3 = (float)c[3] + b4[t].w;
            int col = t * 16 + quad * 4;
            if (last) {
                *(float4*)(fm + (size_t)node * D + col) = make_float4(v0, v1, v2, v3);
            } else {
                union { __half2 h2[2]; uint2 u; } p;
                p.h2[0] = __floats2half2_rn(fmaxf(v0, 0.f) * dv, fmaxf(v1, 0.f) * dv);
                p.h2[1] = __floats2half2_rn(fmaxf(v2, 0.f) * dv, fmaxf(v3, 0.f) * dv);
                *(uint2*)(gm + (size_t)node * D + col) = p.u;
            }
        }
    }
}

// ---------- host ----------

extern "C" void kernel_launch(void* const* d_in, const int* in_sizes, int n_in,
                              void* d_out, int out_size, void* d_ws, size_t ws_size,
                              hipStream_t stream) {
    (void)in_sizes; (void)n_in; (void)out_size; (void)ws_size;
    const float* x  = (const float*)d_in[0];
    const int*   ei = (const int*)d_in[1];
    const float* W  = (const float*)d_in[2];
    const float* b  = (const float*)d_in[3];
    float* out = (float*)d_out;

    char* ws = (char*)d_ws;
    size_t o = 0;
    auto take = [&](size_t bytes) -> void* {
        void* p = ws + o;
        o = (o + bytes + 255) & ~(size_t)255;
        return p;
    };
    float*          dinv      = (float*) take((size_t)N_MEMBERS * N_NODES * 4);
    int*            off       = (int*)   take((size_t)N_MEMBERS * OFF_STRIDE * 4);
    int*            binCursor = (int*)   take((size_t)N_MEMBERS * NBINS * 4);
    int*            bbase     = (int*)   take((size_t)N_MEMBERS * NBINS * 4);
    unsigned short* csr_src   = (unsigned short*)take((size_t)N_MEMBERS * N_EDGES * 2);
    __half*         Wsplit    = (__half*)take((size_t)N_MEMBERS * N_LAYERS * 8192 * 2);
    __half*         gbuf      = (__half*)take((size_t)N_MEMBERS * N_NODES * D * 2);
    __half*         Sbuf      = (__half*)take((size_t)N_MEMBERS * N_NODES * D * 2);
    // binned staging (10.5 MB) aliases Sbuf (16 MB): binned dies at bin_build_k;
    // Sbuf is first written by aggregate_k (layer 0), strictly after.
    unsigned int*   binned    = (unsigned int*)Sbuf;

    hipMemsetAsync(binCursor, 0, (size_t)N_MEMBERS * NBINS * 4, stream);

    presplit_k<<<dim3(N_MEMBERS * N_LAYERS * 512 / 256), 256, 0, stream>>>(W, Wsplit);
    bin_scatter_k<<<dim3(N_EDGES / EDGES_PER_WG, N_MEMBERS), 256, 0, stream>>>(
        ei, binCursor, binned);
    scan_bins_k<<<dim3(N_MEMBERS), 256, 0, stream>>>(binCursor, bbase);
    bin_build_k<<<dim3(NBINS, N_MEMBERS), 256, 0, stream>>>(
        binned, binCursor, bbase, off, dinv, csr_src);
    // g_0 = fp16(dinv .* x)  (needs dinv -> after bin_build_k)
    prescale_k<<<dim3((N_MEMBERS * N_NODES * D / 8) / 256), 256, 0, stream>>>(
        x, dinv, gbuf);

    for (int j = 0; j < N_LAYERS; j++) {
        // flattened grid: member decoded from (blockIdx.x & 7) >> 2 (XCD pinning)
        aggregate_k<<<dim3(N_MEMBERS * (N_NODES / 16)), 256, 0, stream>>>(
            gbuf, Sbuf, off, csr_src, dinv);
        gemm_f16_k<<<dim3(N_NODES / 128, N_MEMBERS), 256, 0, stream>>>(
            Sbuf, Wsplit, dinv, b, gbuf, out, j, (j == N_LAYERS - 1) ? 1 : 0);
    }
}